// Round 1
// baseline (110.438 us; speedup 1.0000x reference)
//
#include <hip/hip_runtime.h>
#include <hip/hip_bf16.h>

#define EPS 1e-12f

typedef __bf16 bf16x8 __attribute__((ext_vector_type(8)));
typedef float  f32x4  __attribute__((ext_vector_type(4)));

// Problem constants (fixed by setup_inputs)
// B=16, N=1024, M=12, F_atom=128, F_bond=32, F_out=128

// ---------------------------------------------------------------------------
// K1: per-(b,n) bond-norm chain up to prod over M  ->  p[b*1024+n]
// One wave (64 lanes) per (b,n) row; 384 contiguous floats per row.
// ---------------------------------------------------------------------------
__global__ __launch_bounds__(256) void k_bond(const float* __restrict__ bond,
                                              float* __restrict__ p_out) {
    const int gwave = (blockIdx.x * 256 + threadIdx.x) >> 6;  // 0..16383
    const int lane  = threadIdx.x & 63;
    const float* base = bond + (size_t)gwave * 384;

    float x[12];
#pragma unroll
    for (int i = 0; i < 6; ++i) {
        float v  = base[lane + 64 * i];
        float sq = v * v;
        // reduce within each 32-lane half (m = 2i for lanes 0-31, 2i+1 for 32-63)
#pragma unroll
        for (int off = 16; off >= 1; off >>= 1) sq += __shfl_xor(sq, off);
        float s0 = __shfl(sq, 0);
        float s1 = __shfl(sq, 32);
        x[2 * i]     = 1.0f / s0;   // (sqrt(s))^-2 == 1/s
        x[2 * i + 1] = 1.0f / s1;
    }
    float sum = 0.f;
#pragma unroll
    for (int m = 0; m < 12; ++m) sum += x[m];
    float d = fmaxf(sum, EPS);
    float prod = 1.f;
#pragma unroll
    for (int m = 0; m < 12; ++m) prod *= x[m] / d;
    if (lane == 0) p_out[gwave] = prod;
}

// ---------------------------------------------------------------------------
// K2: blocks 0..15  : normalize over B, reciprocal, normalize over N -> scale
//     blocks 16..31 : W (128x128 f32, row-major [k][j]) -> Wt bf16 [j][k]
// ---------------------------------------------------------------------------
__global__ __launch_bounds__(256) void k_norm(const float* __restrict__ p,
                                              const float* __restrict__ W,
                                              float* __restrict__ scale,
                                              __bf16* __restrict__ Wt) {
    const int t = threadIdx.x;
    if (blockIdx.x < 16) {
        const int b = blockIdx.x;
        float r[4];
        float partial = 0.f;
#pragma unroll
        for (int i = 0; i < 4; ++i) {
            int n = t + 256 * i;
            float cs = 0.f;
#pragma unroll
            for (int bb = 0; bb < 16; ++bb) cs += p[bb * 1024 + n];
            float y = p[b * 1024 + n] / fmaxf(cs, EPS);
            r[i] = 1.0f / y;
            partial += r[i];
        }
        __shared__ float red[4];
        float v = partial;
#pragma unroll
        for (int off = 32; off >= 1; off >>= 1) v += __shfl_xor(v, off);
        if ((t & 63) == 0) red[t >> 6] = v;
        __syncthreads();
        float S = fmaxf(red[0] + red[1] + red[2] + red[3], EPS);
#pragma unroll
        for (int i = 0; i < 4; ++i) {
            int n = t + 256 * i;
            scale[b * 1024 + n] = r[i] / S;
        }
    } else {
        const int kb = blockIdx.x - 16;  // 8 k-rows of W per block
        for (int idx = t; idx < 8 * 128; idx += 256) {
            int k = kb * 8 + (idx >> 7);
            int j = idx & 127;
            Wt[j * 128 + k] = (__bf16)W[k * 128 + j];
        }
    }
}

// ---------------------------------------------------------------------------
// K3: gather-mean + scale -> u (LDS, bf16) -> MFMA GEMM with Wt -> bias+relu
// 32 rows per block, 256 threads (4 waves). Each wave: 16 rows x 64 cols.
// ---------------------------------------------------------------------------
__global__ __launch_bounds__(256) void k_main(const float* __restrict__ atom,
                                              const int* __restrict__ adj,
                                              const float* __restrict__ scale,
                                              const __bf16* __restrict__ Wt,
                                              const float* __restrict__ bias,
                                              float* __restrict__ out) {
    __shared__ __bf16 uA[32][136];   // stride 136 (17*8): 16B-aligned rows, benign banking
    __shared__ float  sScale[32];
    __shared__ int    sAdj[32 * 12];

    const int t = threadIdx.x;
    const int rowbase = blockIdx.x * 32;        // 1024 % 32 == 0 -> block within one batch
    const int b = rowbase >> 10;

    if (t < 32) sScale[t] = scale[rowbase + t];
    for (int idx = t; idx < 32 * 12; idx += 256) sAdj[idx] = adj[rowbase * 12 + idx];
    __syncthreads();

    // Phase 1: u[r][j] = (atom[row][j] + mean_m atom[b, adj[row][m]][j]) * scale[row]
    {
        const int j = t & 127;
        const int half = t >> 7;
        const float* atomB = atom + (size_t)b * (1024 * 128);
#pragma unroll 4
        for (int r = half; r < 32; r += 2) {
            float accn = 0.f;
#pragma unroll
            for (int m = 0; m < 12; ++m) {
                int idx = sAdj[r * 12 + m];
                accn += atomB[idx * 128 + j];
            }
            float u = (atom[(size_t)(rowbase + r) * 128 + j] + accn * (1.0f / 12.0f)) * sScale[r];
            uA[r][j] = (__bf16)u;
        }
    }
    __syncthreads();

    // Phase 2: per-wave 16x64 tile via mfma_f32_16x16x32_bf16
    const int wave = t >> 6, lane = t & 63;
    const int r0 = (wave >> 1) * 16;
    const int c0 = (wave & 1) * 64;
    const int quad = lane >> 4, lrow = lane & 15;

    bf16x8 aF[4];
#pragma unroll
    for (int kc = 0; kc < 4; ++kc)
        aF[kc] = *(const bf16x8*)&uA[r0 + lrow][kc * 32 + quad * 8];

    f32x4 acc[4];
#pragma unroll
    for (int nt = 0; nt < 4; ++nt) acc[nt] = (f32x4){0.f, 0.f, 0.f, 0.f};

#pragma unroll
    for (int nt = 0; nt < 4; ++nt) {
        const int col = c0 + nt * 16 + lrow;
        const __bf16* wb = Wt + col * 128 + quad * 8;
#pragma unroll
        for (int kc = 0; kc < 4; ++kc) {
            bf16x8 bF = *(const bf16x8*)(wb + kc * 32);
            acc[nt] = __builtin_amdgcn_mfma_f32_16x16x32_bf16(aF[kc], bF, acc[nt], 0, 0, 0);
        }
    }

    // Epilogue: C/D layout col=lane&15, row=quad*4+reg
#pragma unroll
    for (int nt = 0; nt < 4; ++nt) {
        const int col = c0 + nt * 16 + lrow;
        const float bv = bias[col];
#pragma unroll
        for (int i = 0; i < 4; ++i) {
            const int r = r0 + quad * 4 + i;
            float v = acc[nt][i] + bv;
            out[(size_t)(rowbase + r) * 128 + col] = fmaxf(v, 0.f);
        }
    }
}

// ---------------------------------------------------------------------------
extern "C" void kernel_launch(void* const* d_in, const int* in_sizes, int n_in,
                              void* d_out, int out_size, void* d_ws, size_t ws_size,
                              hipStream_t stream) {
    const float* atom = (const float*)d_in[0];
    const float* bond = (const float*)d_in[1];
    const int*   adj  = (const int*)d_in[2];
    const float* W    = (const float*)d_in[3];
    const float* bias = (const float*)d_in[4];
    float* out = (float*)d_out;

    char* ws = (char*)d_ws;
    float*  p     = (float*)ws;                // 16384 f32 = 64 KB
    float*  scale = (float*)(ws + 65536);      // 16384 f32 = 64 KB
    __bf16* Wt    = (__bf16*)(ws + 131072);    // 16384 bf16 = 32 KB

    hipLaunchKernelGGL(k_bond, dim3(4096), dim3(256), 0, stream, bond, p);
    hipLaunchKernelGGL(k_norm, dim3(32),   dim3(256), 0, stream, p, W, scale, Wt);
    hipLaunchKernelGGL(k_main, dim3(512),  dim3(256), 0, stream, atom, adj, scale, Wt, bias, out);
}

// Round 3
// 104.481 us; speedup vs baseline: 1.0570x; 1.0570x over previous
//
#include <hip/hip_runtime.h>
#include <hip/hip_bf16.h>

#define EPS 1e-12f

typedef __bf16 bf16x8 __attribute__((ext_vector_type(8)));
typedef float  f32x4  __attribute__((ext_vector_type(4)));

// Problem constants: B=16, N=1024, M=12, F_atom=128, F_bond=32, F_out=128

// ---------------------------------------------------------------------------
// K1 blocks 0..255 : bond-norm chain -> p[row], 4 threads per row.
//    Each thread owns m = 3q..3q+2 (96 contiguous floats, 24 float4 loads).
//    p = (prod_m x_m) / d^12, d = max(sum_m x_m, EPS), x_m = 1/||bond_m||^2
// K1 blocks 256..259 : W (128x128 f32 [k][j]) -> Wt bf16 [j][k]
// ---------------------------------------------------------------------------
__global__ __launch_bounds__(256) void k_bond(const float* __restrict__ bond,
                                              const float* __restrict__ W,
                                              float* __restrict__ p_out,
                                              __bf16* __restrict__ Wt) {
    const int t = threadIdx.x;
    if (blockIdx.x < 256) {
        const int gtid = blockIdx.x * 256 + t;
        const int row  = gtid >> 2;      // 0..16383
        const int q    = gtid & 3;       // part: m = 3q..3q+2
        const float* base = bond + (size_t)row * 384 + q * 96;

        float x[3];
#pragma unroll
        for (int mm = 0; mm < 3; ++mm) {
            float s = 0.f;
#pragma unroll
            for (int j = 0; j < 8; ++j) {
                f32x4 v = *(const f32x4*)(base + mm * 32 + j * 4);
                s = fmaf(v.x, v.x, s);
                s = fmaf(v.y, v.y, s);
                s = fmaf(v.z, v.z, s);
                s = fmaf(v.w, v.w, s);
            }
            x[mm] = 1.0f / s;            // (sqrt(s))^-2 == 1/s
        }
        float sum  = x[0] + x[1] + x[2];
        float prod = x[0] * x[1] * x[2];
        // reduce over the 4-lane cluster (lanes t, t^1, t^2, t^3 — same wave)
        sum  += __shfl_xor(sum, 1);  prod *= __shfl_xor(prod, 1);
        sum  += __shfl_xor(sum, 2);  prod *= __shfl_xor(prod, 2);
        if (q == 0) {
            float d   = fmaxf(sum, EPS);
            float d2  = d * d;
            float d3  = d2 * d;
            float d6  = d3 * d3;
            float d12 = d6 * d6;
            p_out[row] = prod / d12;
        }
    } else {
        // transpose W -> Wt (bf16), 4 blocks x 4096 elements
        const int base = (blockIdx.x - 256) * 4096;
#pragma unroll
        for (int i = 0; i < 16; ++i) {
            int idx = base + t + 256 * i;
            int k = idx >> 7, j = idx & 127;
            Wt[j * 128 + k] = (__bf16)W[idx];
        }
    }
}

// ---------------------------------------------------------------------------
// K2: per-block: (a) redundant scale computation from p (L2-served),
//     (b) gather-mean + scale -> u (LDS bf16), (c) MFMA GEMM + bias + relu.
// 32 rows per block, 256 threads (4 waves), each wave a 16x64 output tile.
// ---------------------------------------------------------------------------
__global__ __launch_bounds__(256) void k_main(const float* __restrict__ atom,
                                              const int* __restrict__ adj,
                                              const float* __restrict__ p,
                                              const __bf16* __restrict__ Wt,
                                              const float* __restrict__ bias,
                                              float* __restrict__ out) {
    __shared__ __bf16 uA[32][136];   // stride 136: 16B-aligned rows, 2-way banking (free)
    __shared__ float  sScale[32];
    __shared__ int    sAdj[32 * 12];
    __shared__ float  red[4];

    const int t = threadIdx.x;
    const int rowbase = blockIdx.x * 32;   // 1024 % 32 == 0 -> block within one batch
    const int b = rowbase >> 10;

    for (int idx = t; idx < 32 * 12; idx += 256) sAdj[idx] = adj[rowbase * 12 + idx];

    // ---- Phase 0: scale[b, n] for our 32 rows (redundant per block, L2-hot) ----
    // r[b,n] = max(sum_bb p[bb,n], EPS) / p[b,n];  scale = r / max(sum_n r, EPS)
    float S_part = 0.f;
#pragma unroll
    for (int i = 0; i < 4; ++i) {
        int n = t + 256 * i;               // LOCAL n in [0,1024)
        float cs = 0.f;
#pragma unroll
        for (int bb = 0; bb < 16; ++bb) cs += p[bb * 1024 + n];
        S_part += fmaxf(cs, EPS) / p[b * 1024 + n];
    }
#pragma unroll
    for (int off = 32; off >= 1; off >>= 1) S_part += __shfl_xor(S_part, off);
    if ((t & 63) == 0) red[t >> 6] = S_part;
    __syncthreads();
    const float S = fmaxf(red[0] + red[1] + red[2] + red[3], EPS);
    if (t < 32) {
        int nl = (rowbase & 1023) + t;     // LOCAL n for our rows (bug fix: was global)
        float cs = 0.f;
#pragma unroll
        for (int bb = 0; bb < 16; ++bb) cs += p[bb * 1024 + nl];
        // p[b*1024 + nl] == p[rowbase + t] (global row)
        sScale[t] = (fmaxf(cs, EPS) / p[rowbase + t]) / S;
    }
    __syncthreads();

    // ---- Phase 1: u[r][j] = (atom[row][j] + mean_m atom[b,adj[row][m]][j]) * scale ----
    {
        const int j = t & 127;
        const int half = t >> 7;
        const float* atomB = atom + (size_t)b * (1024 * 128);
#pragma unroll 4
        for (int r = half; r < 32; r += 2) {
            float accn = 0.f;
#pragma unroll
            for (int m = 0; m < 12; ++m) {
                int idx = sAdj[r * 12 + m];
                accn += atomB[idx * 128 + j];
            }
            float u = (atom[(size_t)(rowbase + r) * 128 + j] + accn * (1.0f / 12.0f)) * sScale[r];
            uA[r][j] = (__bf16)u;
        }
    }
    __syncthreads();

    // ---- Phase 2: per-wave 16x64 tile via mfma_f32_16x16x32_bf16 ----
    const int wave = t >> 6, lane = t & 63;
    const int r0 = (wave >> 1) * 16;
    const int c0 = (wave & 1) * 64;
    const int quad = lane >> 4, lrow = lane & 15;

    bf16x8 aF[4];
#pragma unroll
    for (int kc = 0; kc < 4; ++kc)
        aF[kc] = *(const bf16x8*)&uA[r0 + lrow][kc * 32 + quad * 8];

    f32x4 acc[4];
#pragma unroll
    for (int nt = 0; nt < 4; ++nt) acc[nt] = (f32x4){0.f, 0.f, 0.f, 0.f};

#pragma unroll
    for (int nt = 0; nt < 4; ++nt) {
        const int col = c0 + nt * 16 + lrow;
        const __bf16* wb = Wt + col * 128 + quad * 8;
#pragma unroll
        for (int kc = 0; kc < 4; ++kc) {
            bf16x8 bF = *(const bf16x8*)(wb + kc * 32);
            acc[nt] = __builtin_amdgcn_mfma_f32_16x16x32_bf16(aF[kc], bF, acc[nt], 0, 0, 0);
        }
    }

    // ---- Epilogue: C/D layout col=lane&15, row=quad*4+reg; nontemporal stores ----
#pragma unroll
    for (int nt = 0; nt < 4; ++nt) {
        const int col = c0 + nt * 16 + lrow;
        const float bv = bias[col];
#pragma unroll
        for (int i = 0; i < 4; ++i) {
            const int r = r0 + quad * 4 + i;
            float v = fmaxf(acc[nt][i] + bv, 0.f);
            __builtin_nontemporal_store(v, &out[(size_t)(rowbase + r) * 128 + col]);
        }
    }
}

// ---------------------------------------------------------------------------
extern "C" void kernel_launch(void* const* d_in, const int* in_sizes, int n_in,
                              void* d_out, int out_size, void* d_ws, size_t ws_size,
                              hipStream_t stream) {
    const float* atom = (const float*)d_in[0];
    const float* bond = (const float*)d_in[1];
    const int*   adj  = (const int*)d_in[2];
    const float* W    = (const float*)d_in[3];
    const float* bias = (const float*)d_in[4];
    float* out = (float*)d_out;

    char* ws = (char*)d_ws;
    float*  p  = (float*)ws;               // 16384 f32 = 64 KB
    __bf16* Wt = (__bf16*)(ws + 65536);    // 16384 bf16 = 32 KB

    hipLaunchKernelGGL(k_bond, dim3(260), dim3(256), 0, stream, bond, W, p, Wt);
    hipLaunchKernelGGL(k_main, dim3(512), dim3(256), 0, stream, atom, adj, p, Wt, bias, out);
}